// Round 1
// baseline (673.400 us; speedup 1.0000x reference)
//
#include <hip/hip_runtime.h>

#define SQ 1024

typedef __attribute__((ext_vector_type(8))) short short8;
typedef __attribute__((ext_vector_type(4))) float f32x4;

#define MFMA16(a,b,c) __builtin_amdgcn_mfma_f32_16x16x32_bf16((a),(b),(c),0,0,0)

static __device__ __forceinline__ float bf2f(unsigned short u){
  union { unsigned int i; float f; } v; v.i = ((unsigned int)u) << 16; return v.f;
}
static __device__ __forceinline__ unsigned short f2bf(float f){
  union { float fv; unsigned int i; } v; v.fv = f;
  unsigned int r = v.i + 0x7fffu + ((v.i >> 16) & 1u);
  return (unsigned short)(r >> 16);
}
static __device__ __forceinline__ void split_store(float val, unsigned short* hi, unsigned short* lo, int idx){
  unsigned short h = f2bf(val);
  hi[idx] = h;
  lo[idx] = f2bf(val - bf2f(h));
}

#define COMP4(v,e) ((e)==0?(v).x:(e)==1?(v).y:(e)==2?(v).z:(v).w)

// ---------------- prep: weight transpose + bf16 hi/lo split ----------------
// Virtual weight matrix [K=384][N=1920] = [Wq|Wk|Wv|Wg|Wo]; output WT[n][k] pairs.
__global__ __launch_bounds__(256) void prep_wt(
    const float* __restrict__ Wq, const float* __restrict__ Wk,
    const float* __restrict__ Wv, const float* __restrict__ Wg,
    const float* __restrict__ Wo,
    unsigned short* __restrict__ wt_hi, unsigned short* __restrict__ wt_lo){
  __shared__ __align__(16) float tile[32][33];
  int nt = blockIdx.x * 32, kt = blockIdx.y * 32;
  int nb = nt / 384;
  const float* W = (nb==0)?Wq:(nb==1)?Wk:(nb==2)?Wv:(nb==3)?Wg:Wo;
  int nn0 = nt - nb*384;
  #pragma unroll
  for (int yy=0; yy<4; yy++){
    int k = kt + threadIdx.y + yy*8;
    tile[threadIdx.y + yy*8][threadIdx.x] = W[k*384 + nn0 + threadIdx.x];
  }
  __syncthreads();
  #pragma unroll
  for (int yy=0; yy<4; yy++){
    int n = nt + threadIdx.y + yy*8;
    int k = kt + threadIdx.x;
    float v = tile[threadIdx.x][threadIdx.y + yy*8];
    split_store(v, wt_hi, wt_lo, n*384 + k);
  }
}

// ww[c][16] = w_z[c]*Wz[c][h] (padded to 16 for b128 LDS reads)
__global__ __launch_bounds__(256) void prep_ww(
    const float* __restrict__ wz, const float* __restrict__ Wz, float* __restrict__ ww){
  int idx = blockIdx.x*256 + threadIdx.x;
  if (idx < 2048){
    int c = idx >> 4, x = idx & 15;
    ww[idx] = (x < 12) ? wz[c]*Wz[c*12 + x] : 0.f;
  }
}

// ---------------- rmsnorm of s -> hi/lo bf16 ----------------
__global__ __launch_bounds__(256) void rmsnorm_s(
    const float* __restrict__ s, const float* __restrict__ w,
    unsigned short* __restrict__ hi, unsigned short* __restrict__ lo){
  int wv = threadIdx.x >> 6, lane = threadIdx.x & 63;
  int row = blockIdx.x*4 + wv;
  const float* sr = s + row*384;
  float v[6]; float ss = 0.f;
  #pragma unroll
  for (int t=0;t<6;t++){ v[t] = sr[lane + t*64]; ss += v[t]*v[t]; }
  #pragma unroll
  for (int m=1;m<64;m<<=1) ss += __shfl_xor(ss, m);
  float rs = rsqrtf(ss*(1.f/384.f) + 1e-5f);
  #pragma unroll
  for (int t=0;t<6;t++){
    int c = lane + t*64;
    split_store(v[t]*rs*w[c], hi, lo, row*384 + c);
  }
}

// ---------------- GEMM1: s_n @ [Wq|Wk|Wv|Wg], hi/lo 3-MFMA ----------------
__global__ __launch_bounds__(256) void gemm_qkvg(
    const unsigned short* __restrict__ Ah, const unsigned short* __restrict__ Al,
    const unsigned short* __restrict__ Bh, const unsigned short* __restrict__ Bl,
    const float* __restrict__ bg,
    unsigned short* __restrict__ q_hi, unsigned short* __restrict__ q_lo,
    unsigned short* __restrict__ k_hi, unsigned short* __restrict__ k_lo,
    unsigned short* __restrict__ v_hi, unsigned short* __restrict__ v_lo,
    float* __restrict__ g){
  __shared__ __align__(16) unsigned short lah[64*40], lal[64*40], lbh[64*40], lbl[64*40];
  int t = threadIdx.x, wv = t >> 6, lane = t & 63;
  int m0 = blockIdx.y * 64, n0 = blockIdx.x * 64;
  int fr = lane & 15, fg = lane >> 4;
  f32x4 z4 = {0.f,0.f,0.f,0.f};
  f32x4 acc[4] = {z4, z4, z4, z4};
  int sr = t >> 2, sc = (t & 3) << 3;
  for (int k0 = 0; k0 < 384; k0 += 32){
    *(short8*)&lah[sr*40 + sc] = *(const short8*)&Ah[(m0+sr)*384 + k0 + sc];
    *(short8*)&lal[sr*40 + sc] = *(const short8*)&Al[(m0+sr)*384 + k0 + sc];
    *(short8*)&lbh[sr*40 + sc] = *(const short8*)&Bh[(n0+sr)*384 + k0 + sc];
    *(short8*)&lbl[sr*40 + sc] = *(const short8*)&Bl[(n0+sr)*384 + k0 + sc];
    __syncthreads();
    short8 a_h = *(short8*)&lah[(wv*16+fr)*40 + (fg<<3)];
    short8 a_l = *(short8*)&lal[(wv*16+fr)*40 + (fg<<3)];
    #pragma unroll
    for (int cf=0; cf<4; cf++){
      short8 b_h = *(short8*)&lbh[(cf*16+fr)*40 + (fg<<3)];
      short8 b_l = *(short8*)&lbl[(cf*16+fr)*40 + (fg<<3)];
      acc[cf] = MFMA16(a_h, b_h, acc[cf]);
      acc[cf] = MFMA16(a_h, b_l, acc[cf]);
      acc[cf] = MFMA16(a_l, b_h, acc[cf]);
    }
    __syncthreads();
  }
  int sec = n0 / 384;
  int nb0 = n0 - sec*384;
  #pragma unroll
  for (int cf=0; cf<4; cf++){
    #pragma unroll
    for (int jj=0; jj<4; jj++){
      int row = m0 + wv*16 + (fg<<2) + jj;
      int nn = nb0 + cf*16 + fr;
      float val = acc[cf][jj];
      int hh = nn >> 5, dd = nn & 31;
      if (sec == 0)      split_store(val, q_hi, q_lo, (hh<<15) + (row<<5) + dd);
      else if (sec == 1) split_store(val, k_hi, k_lo, (hh<<15) + (row<<5) + dd);
      else if (sec == 2) split_store(val, v_hi, v_lo, (hh<<15) + dd*SQ + row);  // V transposed [h][d][j]
      else               g[row*384 + nn] = val + bg[nn];
    }
  }
}

// ---------------- bias kernel: 512MB z stream, fused rmsnorm+proj+mask ----------------
__global__ __launch_bounds__(256,3) void bias_k(
    const float* __restrict__ z, const int* __restrict__ zm,
    const float* __restrict__ ww, float* __restrict__ bias){
  __shared__ __align__(16) float wwl[2048];
  int t = threadIdx.x;
  for (int idx = t; idx < 2048; idx += 256) wwl[idx] = ww[idx];
  __syncthreads();
  int i = blockIdx.x;
  const float* zr = z + (size_t)i * (SQ*128);
  float acc[4][12];
  float ssq[4];
  #pragma unroll
  for (int p=0;p<4;p++){ ssq[p]=0.f;
    #pragma unroll
    for (int hh=0;hh<12;hh++) acc[p][hh]=0.f; }
  for (int cc=0; cc<128; cc+=16){
    float4 zv[4][4];
    #pragma unroll
    for (int p=0;p<4;p++){
      const float* zp = zr + (t + p*256)*128 + cc;
      zv[p][0] = *(const float4*)(zp);
      zv[p][1] = *(const float4*)(zp+4);
      zv[p][2] = *(const float4*)(zp+8);
      zv[p][3] = *(const float4*)(zp+12);
    }
    #pragma unroll
    for (int e=0; e<16; e++){
      int c = cc + e;
      float4 w0 = *(const float4*)&wwl[(c<<4)];
      float4 w1 = *(const float4*)&wwl[(c<<4)+4];
      float4 w2 = *(const float4*)&wwl[(c<<4)+8];
      #pragma unroll
      for (int p=0;p<4;p++){
        float zc = COMP4(zv[p][e>>2], (e&3));
        ssq[p] = fmaf(zc, zc, ssq[p]);
        acc[p][0]=fmaf(zc,w0.x,acc[p][0]);  acc[p][1]=fmaf(zc,w0.y,acc[p][1]);
        acc[p][2]=fmaf(zc,w0.z,acc[p][2]);  acc[p][3]=fmaf(zc,w0.w,acc[p][3]);
        acc[p][4]=fmaf(zc,w1.x,acc[p][4]);  acc[p][5]=fmaf(zc,w1.y,acc[p][5]);
        acc[p][6]=fmaf(zc,w1.z,acc[p][6]);  acc[p][7]=fmaf(zc,w1.w,acc[p][7]);
        acc[p][8]=fmaf(zc,w2.x,acc[p][8]);  acc[p][9]=fmaf(zc,w2.y,acc[p][9]);
        acc[p][10]=fmaf(zc,w2.z,acc[p][10]); acc[p][11]=fmaf(zc,w2.w,acc[p][11]);
      }
    }
  }
  #pragma unroll
  for (int p=0;p<4;p++){
    int j = t + p*256;
    float rs = rsqrtf(ssq[p]*(1.0f/128.0f) + 1e-5f);
    float mk = (zm[i*SQ + j] != 0) ? 0.0f : -1.0e9f;
    size_t base = (size_t)i*SQ + j;
    #pragma unroll
    for (int hh=0;hh<12;hh++)
      bias[(size_t)hh*((size_t)SQ*SQ) + base] = fmaf(acc[p][hh], rs, mk);
  }
}

// ---------------- attention: wave-private 4 rows, no barriers ----------------
__global__ __launch_bounds__(256) void attn_k(
    const unsigned short* __restrict__ qh_, const unsigned short* __restrict__ ql_,
    const unsigned short* __restrict__ kh_, const unsigned short* __restrict__ kl_,
    const unsigned short* __restrict__ vh_, const unsigned short* __restrict__ vl_,
    const float* __restrict__ bias,
    unsigned short* __restrict__ oh_, unsigned short* __restrict__ ol_){
  __shared__ __align__(16) float Sl[16][SQ];   // exactly 64 KB, rows wave-private
  int t = threadIdx.x, wv = t >> 6, lane = t & 63;
  int h = blockIdx.x >> 6;
  int i0 = (blockIdx.x & 63) << 4;
  int fr = lane & 15, fg = lane >> 4;
  int hbase = h << 15;
  const unsigned short* qh = qh_ + hbase; const unsigned short* ql = ql_ + hbase;
  const unsigned short* kh = kh_ + hbase; const unsigned short* kl = kl_ + hbase;
  const unsigned short* vh = vh_ + hbase; const unsigned short* vl = vl_ + hbase;
  int r0 = i0 + (wv << 2);

  short8 aqh = {0,0,0,0,0,0,0,0}, aql = {0,0,0,0,0,0,0,0};
  if (fr < 4){
    aqh = *(const short8*)&qh[((r0 + fr) << 5) + (fg << 3)];
    aql = *(const short8*)&ql[((r0 + fr) << 5) + (fg << 3)];
  }
  const float scale = 0.17677669529663687f;  // 1/sqrt(32)

  // QK^T (hi/lo 3-MFMA) + bias + mask -> Sl
  for (int jt = 0; jt < 64; jt++){
    int j0 = jt << 4;
    short8 bkh = *(const short8*)&kh[((j0 + fr) << 5) + (fg << 3)];
    short8 bkl = *(const short8*)&kl[((j0 + fr) << 5) + (fg << 3)];
    f32x4 a = {0.f,0.f,0.f,0.f};
    a = MFMA16(aqh, bkh, a);
    a = MFMA16(aqh, bkl, a);
    a = MFMA16(aql, bkh, a);
    if (lane < 16){
      #pragma unroll
      for (int rr=0; rr<4; rr++){
        float b = bias[(size_t)h*((size_t)SQ*SQ) + (size_t)(r0+rr)*SQ + j0 + lane];
        Sl[(wv<<2)+rr][j0+lane] = fmaf(a[rr], scale, b);
      }
    }
  }

  // softmax: row = fg (4 rows/wave, 16 lanes/row); bank-rotated scans
  float* Sr = &Sl[(wv<<2)+fg][0];
  float mx = -3.0e38f;
  for (int tt=0; tt<64; tt++){
    int j = (fr + (tt<<4) + (fg<<3)) & 1023;
    mx = fmaxf(mx, Sr[j]);
  }
  mx = fmaxf(mx, __shfl_xor(mx, 1));
  mx = fmaxf(mx, __shfl_xor(mx, 2));
  mx = fmaxf(mx, __shfl_xor(mx, 4));
  mx = fmaxf(mx, __shfl_xor(mx, 8));
  float sm = 0.f;
  for (int tt=0; tt<64; tt++){
    int j = (fr + (tt<<4) + (fg<<3)) & 1023;
    float e = __expf(Sr[j] - mx);
    sm += e;
    Sr[j] = e;   // store unnormalized P (fp32)
  }
  sm += __shfl_xor(sm, 1);
  sm += __shfl_xor(sm, 2);
  sm += __shfl_xor(sm, 4);
  sm += __shfl_xor(sm, 8);
  float linv = 1.0f / sm;
  float li0 = __shfl(linv, 0), li1 = __shfl(linv, 16), li2 = __shfl(linv, 32), li3 = __shfl(linv, 48);

  // PV (hi/lo 3-MFMA), exp values read from LDS, split to bf16 on the fly
  f32x4 o0 = {0.f,0.f,0.f,0.f}, o1 = {0.f,0.f,0.f,0.f};
  for (int k0 = 0; k0 < SQ; k0 += 32){
    float4 pa = {0.f,0.f,0.f,0.f}, pb = {0.f,0.f,0.f,0.f};
    if (fr < 4){
      const float* pp = &Sl[(wv<<2)+fr][k0 + (fg<<3)];
      pa = *(const float4*)pp;
      pb = *(const float4*)(pp+4);
    }
    short8 ph = {0,0,0,0,0,0,0,0}, pl = {0,0,0,0,0,0,0,0};
    #pragma unroll
    for (int e2=0; e2<8; e2++){
      float pv = (e2 < 4) ? COMP4(pa, e2) : COMP4(pb, (e2-4));
      unsigned short hbv = f2bf(pv);
      ph[e2] = (short)hbv;
      pl[e2] = (short)f2bf(pv - bf2f(hbv));
    }
    short8 v0h = *(const short8*)&vh[(fr)*SQ + k0 + (fg<<3)];
    short8 v0l = *(const short8*)&vl[(fr)*SQ + k0 + (fg<<3)];
    short8 v1h = *(const short8*)&vh[(16+fr)*SQ + k0 + (fg<<3)];
    short8 v1l = *(const short8*)&vl[(16+fr)*SQ + k0 + (fg<<3)];
    o0 = MFMA16(ph, v0h, o0); o0 = MFMA16(ph, v0l, o0); o0 = MFMA16(pl, v0h, o0);
    o1 = MFMA16(ph, v1h, o1); o1 = MFMA16(ph, v1l, o1); o1 = MFMA16(pl, v1h, o1);
  }
  float liA[4] = {li0, li1, li2, li3};
  if (lane < 16){
    #pragma unroll
    for (int rr=0; rr<4; rr++){
      int orow = r0 + rr;
      float va = o0[rr] * liA[rr];
      float vb = o1[rr] * liA[rr];
      split_store(va, oh_, ol_, orow*384 + (h<<5) + fr);
      split_store(vb, oh_, ol_, orow*384 + (h<<5) + 16 + fr);
    }
  }
}

// ---------------- GEMM2: (o @ Wo + bo) * g -> fp32 out ----------------
__global__ __launch_bounds__(256) void gemm_out_k(
    const unsigned short* __restrict__ Ah, const unsigned short* __restrict__ Al,
    const unsigned short* __restrict__ Bh, const unsigned short* __restrict__ Bl,
    const float* __restrict__ bo, const float* __restrict__ g,
    float* __restrict__ out){
  __shared__ __align__(16) unsigned short lah[64*40], lal[64*40], lbh[64*40], lbl[64*40];
  int t = threadIdx.x, wv = t >> 6, lane = t & 63;
  int m0 = blockIdx.y * 64, n0 = blockIdx.x * 64;
  int fr = lane & 15, fg = lane >> 4;
  f32x4 z4 = {0.f,0.f,0.f,0.f};
  f32x4 acc[4] = {z4, z4, z4, z4};
  int sr = t >> 2, sc = (t & 3) << 3;
  for (int k0 = 0; k0 < 384; k0 += 32){
    *(short8*)&lah[sr*40 + sc] = *(const short8*)&Ah[(m0+sr)*384 + k0 + sc];
    *(short8*)&lal[sr*40 + sc] = *(const short8*)&Al[(m0+sr)*384 + k0 + sc];
    *(short8*)&lbh[sr*40 + sc] = *(const short8*)&Bh[(n0+sr)*384 + k0 + sc];
    *(short8*)&lbl[sr*40 + sc] = *(const short8*)&Bl[(n0+sr)*384 + k0 + sc];
    __syncthreads();
    short8 a_h = *(short8*)&lah[(wv*16+fr)*40 + (fg<<3)];
    short8 a_l = *(short8*)&lal[(wv*16+fr)*40 + (fg<<3)];
    #pragma unroll
    for (int cf=0; cf<4; cf++){
      short8 b_h = *(short8*)&lbh[(cf*16+fr)*40 + (fg<<3)];
      short8 b_l = *(short8*)&lbl[(cf*16+fr)*40 + (fg<<3)];
      acc[cf] = MFMA16(a_h, b_h, acc[cf]);
      acc[cf] = MFMA16(a_h, b_l, acc[cf]);
      acc[cf] = MFMA16(a_l, b_h, acc[cf]);
    }
    __syncthreads();
  }
  #pragma unroll
  for (int cf=0; cf<4; cf++){
    #pragma unroll
    for (int jj=0; jj<4; jj++){
      int row = m0 + wv*16 + (fg<<2) + jj;
      int col = n0 + cf*16 + fr;
      out[row*384 + col] = (acc[cf][jj] + bo[col]) * g[row*384 + col];
    }
  }
}

// ---------------- launch ----------------
extern "C" void kernel_launch(void* const* d_in, const int* in_sizes, int n_in,
                              void* d_out, int out_size, void* d_ws, size_t ws_size,
                              hipStream_t stream) {
  const float* s   = (const float*)d_in[0];
  const float* z   = (const float*)d_in[1];
  const int*   zm  = (const int*)d_in[2];
  const float* w_s = (const float*)d_in[3];
  const float* w_z = (const float*)d_in[4];
  const float* Wz  = (const float*)d_in[5];
  const float* Wq  = (const float*)d_in[6];
  const float* Wk  = (const float*)d_in[7];
  const float* Wv  = (const float*)d_in[8];
  const float* Wg  = (const float*)d_in[9];
  const float* bg  = (const float*)d_in[10];
  const float* Wo  = (const float*)d_in[11];
  const float* bo  = (const float*)d_in[12];
  float* out = (float*)d_out;
  char* ws = (char*)d_ws;

  unsigned short* s_hi  = (unsigned short*)(ws + 0);
  unsigned short* s_lo  = (unsigned short*)(ws + 786432);
  unsigned short* wt_hi = (unsigned short*)(ws + 1572864);   // [1920][384]
  unsigned short* wt_lo = (unsigned short*)(ws + 3047424);
  float*          ww    = (float*)(ws + 4521984);            // [128][16]
  unsigned short* q_hi  = (unsigned short*)(ws + 4530176);   // [12][1024][32]
  unsigned short* q_lo  = (unsigned short*)(ws + 5316608);
  unsigned short* k_hi  = (unsigned short*)(ws + 6103040);
  unsigned short* k_lo  = (unsigned short*)(ws + 6889472);
  unsigned short* v_hi  = (unsigned short*)(ws + 7675904);   // [12][32][1024] (transposed)
  unsigned short* v_lo  = (unsigned short*)(ws + 8462336);
  float*          gbuf  = (float*)(ws + 9248768);            // [1024][384] fp32
  unsigned short* o_hi  = (unsigned short*)(ws + 10821632);  // [1024][384]
  unsigned short* o_lo  = (unsigned short*)(ws + 11608064);
  float*          biasb = (float*)(ws + 12394496);           // [12][1024][1024] fp32, 48MB

  prep_wt<<<dim3(60,12), dim3(32,8), 0, stream>>>(Wq, Wk, Wv, Wg, Wo, wt_hi, wt_lo);
  prep_ww<<<8, 256, 0, stream>>>(w_z, Wz, ww);
  rmsnorm_s<<<256, 256, 0, stream>>>(s, w_s, s_hi, s_lo);
  gemm_qkvg<<<dim3(24,16), 256, 0, stream>>>(s_hi, s_lo, wt_hi, wt_lo, bg,
                                             q_hi, q_lo, k_hi, k_lo, v_hi, v_lo, gbuf);
  bias_k<<<1024, 256, 0, stream>>>(z, zm, ww, biasb);
  attn_k<<<768, 256, 0, stream>>>(q_hi, q_lo, k_hi, k_lo, v_hi, v_lo, biasb, o_hi, o_lo);
  gemm_out_k<<<dim3(6,16), 256, 0, stream>>>(o_hi, o_lo,
                                             wt_hi + 1536*384, wt_lo + 1536*384,
                                             bo, gbuf, out);
}